// Round 3
// baseline (162.486 us; speedup 1.0000x reference)
//
#include <hip/hip_runtime.h>
#include <hip/hip_bf16.h>
#include <cstdint>

#define SEQ   2048
#define HD    64
#define NBH   32
#define QBLK  64
#define KVBLK 64
#define NQT   (SEQ / QBLK)  // 32
// scale = 1/sqrt(64) * log2(e)  (softmax done in exp2 domain)
#define QSC   0.18033688011112042f

typedef __attribute__((ext_vector_type(8))) short short8;
typedef __attribute__((ext_vector_type(4))) float floatx4;

#if __has_builtin(__builtin_amdgcn_exp2f)
#define EXP2(x) __builtin_amdgcn_exp2f(x)
#else
#define EXP2(x) __expf((x) * 0.69314718055994531f)
#endif

static __device__ __forceinline__ short f2bf(float f) {
    union { float f; unsigned u; } x; x.f = f;
    return (short)((x.u + 0x7fffu + ((x.u >> 16) & 1u)) >> 16);  // RNE
}
static __device__ __forceinline__ unsigned pkbf(float a, float b) {
    __hip_bfloat162 h = __float22bfloat162_rn(make_float2(a, b));
    union { __hip_bfloat162 h; unsigned u; } c; c.h = h; return c.u;
}

// ---------------- prep kernels ----------------

__global__ __launch_bounds__(256)
void conv_k_kernel(const float* __restrict__ K, short* __restrict__ Kb) {
    size_t i = ((size_t)blockIdx.x * 256 + threadIdx.x) * 8;
    float4 a = *(const float4*)(K + i);
    float4 b = *(const float4*)(K + i + 4);
    union { unsigned u[4]; short8 s; } cv;
    cv.u[0] = pkbf(a.x, a.y); cv.u[1] = pkbf(a.z, a.w);
    cv.u[2] = pkbf(b.x, b.y); cv.u[3] = pkbf(b.z, b.w);
    *(short8*)(Kb + i) = cv.s;
}

__global__ __launch_bounds__(256)
void trans_v_kernel(const float* __restrict__ V, short* __restrict__ Vt) {
    __shared__ __align__(16) short Vs[64][72];
    const int tid = threadIdx.x;
    const int bh = blockIdx.x >> 5;
    const int t  = blockIdx.x & 31;
    const float* src = V + ((size_t)bh * SEQ + (size_t)t * 64) * HD;
    #pragma unroll
    for (int i = 0; i < 4; ++i) {
        int idx = i * 256 + tid;          // float4 index over 64*64/4
        int r = idx >> 4; int c = (idx & 15) * 4;
        float4 f = *(const float4*)(src + r * HD + c);
        Vs[c + 0][r] = f2bf(f.x); Vs[c + 1][r] = f2bf(f.y);
        Vs[c + 2][r] = f2bf(f.z); Vs[c + 3][r] = f2bf(f.w);
    }
    __syncthreads();
    short* dst = Vt + (size_t)bh * HD * SEQ + t * 64;
    #pragma unroll
    for (int i = 0; i < 2; ++i) {
        int idx = i * 256 + tid;          // 16B-chunk index over 64 rows * 8
        int d = idx >> 3; int j = idx & 7;
        short8 v = *(const short8*)&Vs[d][j * 8];
        *(short8*)(dst + (size_t)d * SEQ + j * 8) = v;
    }
}

// ---------------- main attention kernel (v3): no K/V LDS staging ----------------
// Waves are fully independent (no __syncthreads). K/V fragments read directly
// from prepped bf16 global; per-bh KV (512 KB) is L2-resident (blocks of one bh
// land on one XCD: blockIdx stride 32 == 0 mod 8).

__global__ __launch_bounds__(256, 2)
void fa_fwd_v3(const float* __restrict__ Q, const short* __restrict__ Kg,
               const short* __restrict__ Vtg, float* __restrict__ O)
{
    const int tid  = threadIdx.x;
    const int lane = tid & 63;
    const int wv   = tid >> 6;
    const int l15  = lane & 15;
    const int lg   = lane >> 4;
    const int dofs = lg * 8;

    const int bh = blockIdx.x & (NBH - 1);
    const int qi = (NQT - 1) - (blockIdx.x >> 5);   // heavy tiles first
    const int qbase = qi * QBLK;

    const float* Qp = Q   + (size_t)bh * SEQ * HD;
    const short* Kp = Kg  + (size_t)bh * SEQ * HD;
    const short* Vp = Vtg + (size_t)bh * HD * SEQ;
    float*       Op = O   + (size_t)bh * SEQ * HD;

    __shared__ __align__(16) short Pl[4][16][72];   // per-wave P tile

    // ---- Q fragments from fp32 global, scale folded, packed bf16 ----
    short8 qfrag[2];
    {
        const float* src = Qp + (size_t)(qbase + wv * 16 + l15) * HD + dofs;
        union { unsigned u[4]; short8 s; } cv;
        float4 f0 = *(const float4*)(src);
        float4 f1 = *(const float4*)(src + 4);
        cv.u[0] = pkbf(f0.x * QSC, f0.y * QSC); cv.u[1] = pkbf(f0.z * QSC, f0.w * QSC);
        cv.u[2] = pkbf(f1.x * QSC, f1.y * QSC); cv.u[3] = pkbf(f1.z * QSC, f1.w * QSC);
        qfrag[0] = cv.s;
        f0 = *(const float4*)(src + 32);
        f1 = *(const float4*)(src + 36);
        cv.u[0] = pkbf(f0.x * QSC, f0.y * QSC); cv.u[1] = pkbf(f0.z * QSC, f0.w * QSC);
        cv.u[2] = pkbf(f1.x * QSC, f1.y * QSC); cv.u[3] = pkbf(f1.z * QSC, f1.w * QSC);
        qfrag[1] = cv.s;
    }

    floatx4 o_acc[4];
    #pragma unroll
    for (int dt = 0; dt < 4; ++dt)
        #pragma unroll
        for (int e = 0; e < 4; ++e) o_acc[dt][e] = 0.0f;
    float m_r[4], l_r[4];
    #pragma unroll
    for (int r = 0; r < 4; ++r) { m_r[r] = -1e30f; l_r[r] = 0.0f; }

    for (int t = 0; t <= qi; ++t) {
        // ---- K fragment loads (direct from global bf16) ----
        short8 ka[4], kb[4];
        #pragma unroll
        for (int n = 0; n < 4; ++n) {
            const short* kr = Kp + (size_t)(t * KVBLK + n * 16 + l15) * HD + dofs;
            ka[n] = *(const short8*)(kr);
            kb[n] = *(const short8*)(kr + 32);
        }
        // ---- V fragment loads issued early; latency hides under softmax ----
        short8 va[4], vb[4];
        #pragma unroll
        for (int dt = 0; dt < 4; ++dt) {
            const short* vr = Vp + (size_t)(dt * 16 + l15) * SEQ + t * KVBLK + dofs;
            va[dt] = *(const short8*)(vr);
            vb[dt] = *(const short8*)(vr + 32);
        }

        // ---- S = (Q*scale) K^T ----
        floatx4 s_acc[4];
        #pragma unroll
        for (int n = 0; n < 4; ++n) {
            floatx4 acc = {0.0f, 0.0f, 0.0f, 0.0f};
            acc = __builtin_amdgcn_mfma_f32_16x16x32_bf16(qfrag[0], ka[n], acc, 0, 0, 0);
            acc = __builtin_amdgcn_mfma_f32_16x16x32_bf16(qfrag[1], kb[n], acc, 0, 0, 0);
            s_acc[n] = acc;
        }

        // ---- causal mask (diagonal tile only) ----
        if (t == qi) {
            #pragma unroll
            for (int n = 0; n < 4; ++n)
                #pragma unroll
                for (int r = 0; r < 4; ++r) {
                    int qr = wv * 16 + lg * 4 + r;
                    int kc = n * 16 + l15;
                    if (kc > qr) s_acc[n][r] = -1e30f;
                }
        }

        // ---- online softmax (exp2 domain) ----
        #pragma unroll
        for (int r = 0; r < 4; ++r) {
            float rmax = fmaxf(fmaxf(s_acc[0][r], s_acc[1][r]),
                               fmaxf(s_acc[2][r], s_acc[3][r]));
            rmax = fmaxf(rmax, __shfl_xor(rmax, 1));
            rmax = fmaxf(rmax, __shfl_xor(rmax, 2));
            rmax = fmaxf(rmax, __shfl_xor(rmax, 4));
            rmax = fmaxf(rmax, __shfl_xor(rmax, 8));
            float mnew  = fmaxf(m_r[r], rmax);
            float alpha = EXP2(m_r[r] - mnew);
            m_r[r] = mnew;
            l_r[r] *= alpha;
            #pragma unroll
            for (int dt = 0; dt < 4; ++dt) o_acc[dt][r] *= alpha;
            float p0 = EXP2(s_acc[0][r] - mnew);
            float p1 = EXP2(s_acc[1][r] - mnew);
            float p2 = EXP2(s_acc[2][r] - mnew);
            float p3 = EXP2(s_acc[3][r] - mnew);
            l_r[r] += (p0 + p1) + (p2 + p3);
            unsigned ua = pkbf(p0, p1), ub = pkbf(p2, p3);
            short* prow = &Pl[wv][lg * 4 + r][l15];
            prow[0]  = (short)(ua & 0xffff);
            prow[16] = (short)(ua >> 16);
            prow[32] = (short)(ub & 0xffff);
            prow[48] = (short)(ub >> 16);
        }
        // wave-local LDS RAW: wait for this wave's ds_writes
        asm volatile("s_waitcnt lgkmcnt(0)" ::: "memory");

        // ---- O += P V ----
        const short8 p0 = *(const short8*)&Pl[wv][l15][dofs];
        const short8 p1 = *(const short8*)&Pl[wv][l15][dofs + 32];
        #pragma unroll
        for (int dt = 0; dt < 4; ++dt) {
            o_acc[dt] = __builtin_amdgcn_mfma_f32_16x16x32_bf16(p0, va[dt], o_acc[dt], 0, 0, 0);
            o_acc[dt] = __builtin_amdgcn_mfma_f32_16x16x32_bf16(p1, vb[dt], o_acc[dt], 0, 0, 0);
        }
    }

    // ---- finalize: reduce l across the 16-lane group, divide, store ----
    #pragma unroll
    for (int r = 0; r < 4; ++r) {
        float l = l_r[r];
        l += __shfl_xor(l, 1);
        l += __shfl_xor(l, 2);
        l += __shfl_xor(l, 4);
        l += __shfl_xor(l, 8);
        l_r[r] = 1.0f / l;
    }
    #pragma unroll
    for (int dt = 0; dt < 4; ++dt)
        #pragma unroll
        for (int r = 0; r < 4; ++r) {
            int row = qbase + wv * 16 + lg * 4 + r;
            Op[(size_t)row * HD + dt * 16 + l15] = o_acc[dt][r] * l_r[r];
        }
}

// ---------------- fallback (round-1 kernel) if ws too small ----------------

__global__ __launch_bounds__(256, 2)
void fa_fwd_v1(const float* __restrict__ Q, const float* __restrict__ K,
               const float* __restrict__ V, float* __restrict__ O)
{
    const int tid  = threadIdx.x;
    const int lane = tid & 63;
    const int wv   = tid >> 6;
    const int l15  = lane & 15;
    const int lg   = lane >> 4;
    const int dofs = lg * 8;
    const int bh = blockIdx.x & (NBH - 1);
    const int qi = (NQT - 1) - (blockIdx.x >> 5);
    const size_t base = (size_t)bh * SEQ * HD;
    const float* Qp = Q + base; const float* Kp = K + base;
    const float* Vp = V + base; float* Op = O + base;
    const int qbase = qi * QBLK;
    __shared__ __align__(16) short K_lds[KVBLK][72];
    __shared__ __align__(16) short Vt_lds[HD][72];
    __shared__ __align__(16) short P_lds[4][16][72];
    short8 qfrag[2];
    {
        const float* src = Qp + (size_t)(qbase + wv * 16 + l15) * HD + dofs;
        #pragma unroll
        for (int c = 0; c < 2; ++c) {
            float4 f0 = *(const float4*)(src + 32 * c);
            float4 f1 = *(const float4*)(src + 32 * c + 4);
            short8 tt;
            tt[0] = f2bf(f0.x * 0.125f); tt[1] = f2bf(f0.y * 0.125f);
            tt[2] = f2bf(f0.z * 0.125f); tt[3] = f2bf(f0.w * 0.125f);
            tt[4] = f2bf(f1.x * 0.125f); tt[5] = f2bf(f1.y * 0.125f);
            tt[6] = f2bf(f1.z * 0.125f); tt[7] = f2bf(f1.w * 0.125f);
            qfrag[c] = tt;
        }
    }
    floatx4 o_acc[4];
    #pragma unroll
    for (int dt = 0; dt < 4; ++dt)
        #pragma unroll
        for (int e = 0; e < 4; ++e) o_acc[dt][e] = 0.0f;
    float m_r[4], l_r[4];
    #pragma unroll
    for (int r = 0; r < 4; ++r) { m_r[r] = -1e30f; l_r[r] = 0.0f; }
    for (int t = 0; t <= qi; ++t) {
        __syncthreads();
        {
            const float4* ks = (const float4*)(Kp + (size_t)t * KVBLK * HD);
            const float4* vs = (const float4*)(Vp + (size_t)t * KVBLK * HD);
            #pragma unroll
            for (int j = 0; j < 4; ++j) {
                int idx = j * 256 + tid;
                int row = idx >> 4;
                int col = (idx & 15) << 2;
                float4 kf = ks[idx];
                K_lds[row][col + 0] = f2bf(kf.x); K_lds[row][col + 1] = f2bf(kf.y);
                K_lds[row][col + 2] = f2bf(kf.z); K_lds[row][col + 3] = f2bf(kf.w);
                float4 vf = vs[idx];
                Vt_lds[col + 0][row] = f2bf(vf.x); Vt_lds[col + 1][row] = f2bf(vf.y);
                Vt_lds[col + 2][row] = f2bf(vf.z); Vt_lds[col + 3][row] = f2bf(vf.w);
            }
        }
        __syncthreads();
        floatx4 s_acc[4];
        #pragma unroll
        for (int n = 0; n < 4; ++n) {
            const short8 k0 = *(const short8*)&K_lds[n * 16 + l15][dofs];
            const short8 k1 = *(const short8*)&K_lds[n * 16 + l15][dofs + 32];
            floatx4 acc = {0.0f, 0.0f, 0.0f, 0.0f};
            acc = __builtin_amdgcn_mfma_f32_16x16x32_bf16(qfrag[0], k0, acc, 0, 0, 0);
            acc = __builtin_amdgcn_mfma_f32_16x16x32_bf16(qfrag[1], k1, acc, 0, 0, 0);
            s_acc[n] = acc;
        }
        if (t == qi) {
            #pragma unroll
            for (int n = 0; n < 4; ++n)
                #pragma unroll
                for (int r = 0; r < 4; ++r) {
                    int qr = wv * 16 + lg * 4 + r;
                    int kc = n * 16 + l15;
                    if (kc > qr) s_acc[n][r] = -1e30f;
                }
        }
        #pragma unroll
        for (int r = 0; r < 4; ++r) {
            float rmax = fmaxf(fmaxf(s_acc[0][r], s_acc[1][r]),
                               fmaxf(s_acc[2][r], s_acc[3][r]));
            rmax = fmaxf(rmax, __shfl_xor(rmax, 1));
            rmax = fmaxf(rmax, __shfl_xor(rmax, 2));
            rmax = fmaxf(rmax, __shfl_xor(rmax, 4));
            rmax = fmaxf(rmax, __shfl_xor(rmax, 8));
            float mnew  = fmaxf(m_r[r], rmax);
            float alpha = __expf(m_r[r] - mnew);
            m_r[r] = mnew;
            l_r[r] *= alpha;
            #pragma unroll
            for (int dt = 0; dt < 4; ++dt) o_acc[dt][r] *= alpha;
            #pragma unroll
            for (int n = 0; n < 4; ++n) {
                float p = __expf(s_acc[n][r] - mnew);
                l_r[r] += p;
                P_lds[wv][lg * 4 + r][n * 16 + l15] = f2bf(p);
            }
        }
        asm volatile("s_waitcnt lgkmcnt(0)" ::: "memory");
        const short8 p0 = *(const short8*)&P_lds[wv][l15][dofs];
        const short8 p1 = *(const short8*)&P_lds[wv][l15][dofs + 32];
        #pragma unroll
        for (int dt = 0; dt < 4; ++dt) {
            const short8 v0 = *(const short8*)&Vt_lds[dt * 16 + l15][dofs];
            const short8 v1 = *(const short8*)&Vt_lds[dt * 16 + l15][dofs + 32];
            o_acc[dt] = __builtin_amdgcn_mfma_f32_16x16x32_bf16(p0, v0, o_acc[dt], 0, 0, 0);
            o_acc[dt] = __builtin_amdgcn_mfma_f32_16x16x32_bf16(p1, v1, o_acc[dt], 0, 0, 0);
        }
    }
    #pragma unroll
    for (int r = 0; r < 4; ++r) {
        float l = l_r[r];
        l += __shfl_xor(l, 1);
        l += __shfl_xor(l, 2);
        l += __shfl_xor(l, 4);
        l += __shfl_xor(l, 8);
        l_r[r] = 1.0f / l;
    }
    #pragma unroll
    for (int dt = 0; dt < 4; ++dt)
        #pragma unroll
        for (int r = 0; r < 4; ++r) {
            int row = qbase + wv * 16 + lg * 4 + r;
            Op[(size_t)row * HD + dt * 16 + l15] = o_acc[dt][r] * l_r[r];
        }
}

extern "C" void kernel_launch(void* const* d_in, const int* in_sizes, int n_in,
                              void* d_out, int out_size, void* d_ws, size_t ws_size,
                              hipStream_t stream) {
    const float* q = (const float*)d_in[0];
    const float* k = (const float*)d_in[1];
    const float* v = (const float*)d_in[2];
    float* o = (float*)d_out;
    (void)in_sizes; (void)n_in; (void)out_size;

    const size_t elems = (size_t)NBH * SEQ * HD;
    const size_t need  = 2 * elems * sizeof(short);
    if (ws_size >= need) {
        short* kb = (short*)d_ws;
        short* vt = kb + elems;
        conv_k_kernel<<<dim3(elems / (256 * 8)), dim3(256), 0, stream>>>(k, kb);
        trans_v_kernel<<<dim3(NBH * 32), dim3(256), 0, stream>>>(v, vt);
        fa_fwd_v3<<<dim3(NBH * NQT), dim3(256), 0, stream>>>(q, kb, vt, o);
    } else {
        fa_fwd_v1<<<dim3(NBH * NQT), dim3(256), 0, stream>>>(q, k, v, o);
    }
}

// Round 4
// 69.224 us; speedup vs baseline: 2.3472x; 2.3472x over previous
//
#include <hip/hip_runtime.h>
#include <hip/hip_bf16.h>
#include <cstdint>

#define SEQ   2048
#define HD    64
#define NBH   32
#define QBLK  64
#define KVBLK 64
#define NQT   (SEQ / QBLK)  // 32
#define LDK   72            // padded LDS stride (shorts): 144B rows, 16B-aligned
// scale = 1/sqrt(64) * log2(e)  (softmax done in exp2 domain)
#define QSC   0.18033688011112042f

typedef __attribute__((ext_vector_type(8))) short short8;
typedef __attribute__((ext_vector_type(4))) float floatx4;

#if __has_builtin(__builtin_amdgcn_exp2f)
#define EXP2(x) __builtin_amdgcn_exp2f(x)
#else
#define EXP2(x) __expf((x) * 0.69314718055994531f)
#endif

static __device__ __forceinline__ short f2bf(float f) {
    union { float f; unsigned u; } x; x.f = f;
    return (short)((x.u + 0x7fffu + ((x.u >> 16) & 1u)) >> 16);  // RNE
}
static __device__ __forceinline__ unsigned pkbf(float a, float b) {
    __hip_bfloat162 h = __float22bfloat162_rn(make_float2(a, b));
    union { __hip_bfloat162 h; unsigned u; } c; c.h = h; return c.u;
}

// ---------------- prep kernels (proven in round 3) ----------------

__global__ __launch_bounds__(256)
void conv_k_kernel(const float* __restrict__ K, short* __restrict__ Kb) {
    size_t i = ((size_t)blockIdx.x * 256 + threadIdx.x) * 8;
    float4 a = *(const float4*)(K + i);
    float4 b = *(const float4*)(K + i + 4);
    union { unsigned u[4]; short8 s; } cv;
    cv.u[0] = pkbf(a.x, a.y); cv.u[1] = pkbf(a.z, a.w);
    cv.u[2] = pkbf(b.x, b.y); cv.u[3] = pkbf(b.z, b.w);
    *(short8*)(Kb + i) = cv.s;
}

__global__ __launch_bounds__(256)
void trans_v_kernel(const float* __restrict__ V, short* __restrict__ Vt) {
    __shared__ __align__(16) short Vs[64][72];
    const int tid = threadIdx.x;
    const int bh = blockIdx.x >> 5;
    const int t  = blockIdx.x & 31;
    const float* src = V + ((size_t)bh * SEQ + (size_t)t * 64) * HD;
    #pragma unroll
    for (int i = 0; i < 4; ++i) {
        int idx = i * 256 + tid;
        int r = idx >> 4; int c = (idx & 15) * 4;
        float4 f = *(const float4*)(src + r * HD + c);
        Vs[c + 0][r] = f2bf(f.x); Vs[c + 1][r] = f2bf(f.y);
        Vs[c + 2][r] = f2bf(f.z); Vs[c + 3][r] = f2bf(f.w);
    }
    __syncthreads();
    short* dst = Vt + (size_t)bh * HD * SEQ + t * 64;
    #pragma unroll
    for (int i = 0; i < 2; ++i) {
        int idx = i * 256 + tid;
        int d = idx >> 3; int j = idx & 7;
        short8 v = *(const short8*)&Vs[d][j * 8];
        *(short8*)(dst + (size_t)d * SEQ + j * 8) = v;
    }
}

// ---------------- main attention kernel (v4) ----------------
// LDS staging of prepped bf16 K / Vt with __syncthreads (round-1 structure),
// linear vector staging (no transpose, no conversion), T14 reg-prefetch of
// tile t+1 issued right after the publish barrier.

__global__ __launch_bounds__(256, 4)
void fa_fwd_v4(const float* __restrict__ Q, const short* __restrict__ Kg,
               const short* __restrict__ Vtg, float* __restrict__ O)
{
    const int tid  = threadIdx.x;
    const int lane = tid & 63;
    const int wv   = tid >> 6;
    const int l15  = lane & 15;
    const int lg   = lane >> 4;
    const int dofs = lg * 8;

    const int bh = blockIdx.x & (NBH - 1);
    const int qi = (NQT - 1) - (blockIdx.x >> 5);   // heavy tiles first
    const int qbase = qi * QBLK;

    const float* Qp = Q   + (size_t)bh * SEQ * HD;
    const short* Kp = Kg  + (size_t)bh * SEQ * HD;
    const short* Vp = Vtg + (size_t)bh * HD * SEQ;
    float*       Op = O   + (size_t)bh * SEQ * HD;

    __shared__ __align__(16) short K_lds[KVBLK][LDK];   // [kv][d]
    __shared__ __align__(16) short Vt_lds[HD][LDK];     // [d][kv]
    __shared__ __align__(16) short Pl[4][16][LDK];      // per-wave P tile

    // staging geometry: 512 short8 chunks per tile; 2 per thread for K, V each
    const int r0 = tid >> 3,         j0 = tid & 7;          // chunks 0..255
    const int r1 = (tid + 256) >> 3, j1 = tid & 7;          // chunks 256..511
    const int kg0 = r0 * HD + j0 * 8, kg1 = r1 * HD + j1 * 8;   // K global (shorts)
    const int vg0 = r0 * SEQ + j0 * 8, vg1 = r1 * SEQ + j1 * 8; // Vt global (shorts)

    // ---- Q fragments from fp32 global, scale folded, packed bf16 ----
    short8 qfrag[2];
    {
        const float* src = Qp + (size_t)(qbase + wv * 16 + l15) * HD + dofs;
        union { unsigned u[4]; short8 s; } cv;
        float4 f0 = *(const float4*)(src);
        float4 f1 = *(const float4*)(src + 4);
        cv.u[0] = pkbf(f0.x * QSC, f0.y * QSC); cv.u[1] = pkbf(f0.z * QSC, f0.w * QSC);
        cv.u[2] = pkbf(f1.x * QSC, f1.y * QSC); cv.u[3] = pkbf(f1.z * QSC, f1.w * QSC);
        qfrag[0] = cv.s;
        f0 = *(const float4*)(src + 32);
        f1 = *(const float4*)(src + 36);
        cv.u[0] = pkbf(f0.x * QSC, f0.y * QSC); cv.u[1] = pkbf(f0.z * QSC, f0.w * QSC);
        cv.u[2] = pkbf(f1.x * QSC, f1.y * QSC); cv.u[3] = pkbf(f1.z * QSC, f1.w * QSC);
        qfrag[1] = cv.s;
    }

    // ---- prologue: prefetch tile 0 into registers ----
    short8 krA, krB, vrA, vrB;
    {
        const short* ks = Kp;
        const short* vs = Vp;
        krA = *(const short8*)(ks + kg0);
        krB = *(const short8*)(ks + kg1);
        vrA = *(const short8*)(vs + vg0);
        vrB = *(const short8*)(vs + vg1);
    }

    floatx4 o_acc[4];
    #pragma unroll
    for (int dt = 0; dt < 4; ++dt)
        #pragma unroll
        for (int e = 0; e < 4; ++e) o_acc[dt][e] = 0.0f;
    float m_r[4], l_r[4];
    #pragma unroll
    for (int r = 0; r < 4; ++r) { m_r[r] = -1e30f; l_r[r] = 0.0f; }

    for (int t = 0; t <= qi; ++t) {
        __syncthreads();   // previous iteration's readers done with LDS
        // ---- publish staged registers to LDS (linear, conflict-free) ----
        *(short8*)&K_lds[r0][j0 * 8]  = krA;
        *(short8*)&K_lds[r1][j1 * 8]  = krB;
        *(short8*)&Vt_lds[r0][j0 * 8] = vrA;
        *(short8*)&Vt_lds[r1][j1 * 8] = vrB;
        __syncthreads();   // tile t visible to all waves

        // ---- issue tile t+1 loads; compute phase hides the latency ----
        if (t < qi) {
            const short* ks = Kp + (size_t)(t + 1) * KVBLK * HD;
            const short* vs = Vp + (t + 1) * KVBLK;
            krA = *(const short8*)(ks + kg0);
            krB = *(const short8*)(ks + kg1);
            vrA = *(const short8*)(vs + vg0);
            vrB = *(const short8*)(vs + vg1);
        }

        // ---- S = (Q*scale) K^T ----
        floatx4 s_acc[4];
        #pragma unroll
        for (int n = 0; n < 4; ++n) {
            const short8 k0 = *(const short8*)&K_lds[n * 16 + l15][dofs];
            const short8 k1 = *(const short8*)&K_lds[n * 16 + l15][dofs + 32];
            floatx4 acc = {0.0f, 0.0f, 0.0f, 0.0f};
            acc = __builtin_amdgcn_mfma_f32_16x16x32_bf16(qfrag[0], k0, acc, 0, 0, 0);
            acc = __builtin_amdgcn_mfma_f32_16x16x32_bf16(qfrag[1], k1, acc, 0, 0, 0);
            s_acc[n] = acc;
        }

        // ---- causal mask (diagonal tile only) ----
        if (t == qi) {
            #pragma unroll
            for (int n = 0; n < 4; ++n)
                #pragma unroll
                for (int r = 0; r < 4; ++r) {
                    int qr = wv * 16 + lg * 4 + r;
                    int kc = n * 16 + l15;
                    if (kc > qr) s_acc[n][r] = -1e30f;
                }
        }

        // ---- online softmax (exp2 domain) ----
        #pragma unroll
        for (int r = 0; r < 4; ++r) {
            float rmax = fmaxf(fmaxf(s_acc[0][r], s_acc[1][r]),
                               fmaxf(s_acc[2][r], s_acc[3][r]));
            rmax = fmaxf(rmax, __shfl_xor(rmax, 1));
            rmax = fmaxf(rmax, __shfl_xor(rmax, 2));
            rmax = fmaxf(rmax, __shfl_xor(rmax, 4));
            rmax = fmaxf(rmax, __shfl_xor(rmax, 8));
            float mnew  = fmaxf(m_r[r], rmax);
            float alpha = EXP2(m_r[r] - mnew);
            m_r[r] = mnew;
            l_r[r] *= alpha;
            #pragma unroll
            for (int dt = 0; dt < 4; ++dt) o_acc[dt][r] *= alpha;
            float p0 = EXP2(s_acc[0][r] - mnew);
            float p1 = EXP2(s_acc[1][r] - mnew);
            float p2 = EXP2(s_acc[2][r] - mnew);
            float p3 = EXP2(s_acc[3][r] - mnew);
            l_r[r] += (p0 + p1) + (p2 + p3);
            unsigned ua = pkbf(p0, p1), ub = pkbf(p2, p3);
            short* prow = &Pl[wv][lg * 4 + r][l15];
            prow[0]  = (short)(ua & 0xffff);
            prow[16] = (short)(ua >> 16);
            prow[32] = (short)(ub & 0xffff);
            prow[48] = (short)(ub >> 16);
        }
        // wave-local LDS RAW: wait for this wave's ds_writes
        asm volatile("s_waitcnt lgkmcnt(0)" ::: "memory");

        // ---- O += P V ----
        const short8 p0 = *(const short8*)&Pl[wv][l15][dofs];
        const short8 p1 = *(const short8*)&Pl[wv][l15][dofs + 32];
        #pragma unroll
        for (int dt = 0; dt < 4; ++dt) {
            const short8 v0 = *(const short8*)&Vt_lds[dt * 16 + l15][dofs];
            const short8 v1 = *(const short8*)&Vt_lds[dt * 16 + l15][dofs + 32];
            o_acc[dt] = __builtin_amdgcn_mfma_f32_16x16x32_bf16(p0, v0, o_acc[dt], 0, 0, 0);
            o_acc[dt] = __builtin_amdgcn_mfma_f32_16x16x32_bf16(p1, v1, o_acc[dt], 0, 0, 0);
        }
    }

    // ---- finalize: reduce l across the 16-lane group, divide, store ----
    #pragma unroll
    for (int r = 0; r < 4; ++r) {
        float l = l_r[r];
        l += __shfl_xor(l, 1);
        l += __shfl_xor(l, 2);
        l += __shfl_xor(l, 4);
        l += __shfl_xor(l, 8);
        l_r[r] = 1.0f / l;
    }
    #pragma unroll
    for (int dt = 0; dt < 4; ++dt)
        #pragma unroll
        for (int r = 0; r < 4; ++r) {
            int row = qbase + wv * 16 + lg * 4 + r;
            Op[(size_t)row * HD + dt * 16 + l15] = o_acc[dt][r] * l_r[r];
        }
}

// ---------------- fallback (round-1 kernel, proven) if ws too small ----------------

__global__ __launch_bounds__(256, 2)
void fa_fwd_v1(const float* __restrict__ Q, const float* __restrict__ K,
               const float* __restrict__ V, float* __restrict__ O)
{
    const int tid  = threadIdx.x;
    const int lane = tid & 63;
    const int wv   = tid >> 6;
    const int l15  = lane & 15;
    const int lg   = lane >> 4;
    const int dofs = lg * 8;
    const int bh = blockIdx.x & (NBH - 1);
    const int qi = (NQT - 1) - (blockIdx.x >> 5);
    const size_t base = (size_t)bh * SEQ * HD;
    const float* Qp = Q + base; const float* Kp = K + base;
    const float* Vp = V + base; float* Op = O + base;
    const int qbase = qi * QBLK;
    __shared__ __align__(16) short K_lds[KVBLK][72];
    __shared__ __align__(16) short Vt_lds[HD][72];
    __shared__ __align__(16) short P_lds[4][16][72];
    short8 qfrag[2];
    {
        const float* src = Qp + (size_t)(qbase + wv * 16 + l15) * HD + dofs;
        #pragma unroll
        for (int c = 0; c < 2; ++c) {
            float4 f0 = *(const float4*)(src + 32 * c);
            float4 f1 = *(const float4*)(src + 32 * c + 4);
            short8 tt;
            tt[0] = f2bf(f0.x * 0.125f); tt[1] = f2bf(f0.y * 0.125f);
            tt[2] = f2bf(f0.z * 0.125f); tt[3] = f2bf(f0.w * 0.125f);
            tt[4] = f2bf(f1.x * 0.125f); tt[5] = f2bf(f1.y * 0.125f);
            tt[6] = f2bf(f1.z * 0.125f); tt[7] = f2bf(f1.w * 0.125f);
            qfrag[c] = tt;
        }
    }
    floatx4 o_acc[4];
    #pragma unroll
    for (int dt = 0; dt < 4; ++dt)
        #pragma unroll
        for (int e = 0; e < 4; ++e) o_acc[dt][e] = 0.0f;
    float m_r[4], l_r[4];
    #pragma unroll
    for (int r = 0; r < 4; ++r) { m_r[r] = -1e30f; l_r[r] = 0.0f; }
    for (int t = 0; t <= qi; ++t) {
        __syncthreads();
        {
            const float4* ks = (const float4*)(Kp + (size_t)t * KVBLK * HD);
            const float4* vs = (const float4*)(Vp + (size_t)t * KVBLK * HD);
            #pragma unroll
            for (int j = 0; j < 4; ++j) {
                int idx = j * 256 + tid;
                int row = idx >> 4;
                int col = (idx & 15) << 2;
                float4 kf = ks[idx];
                K_lds[row][col + 0] = f2bf(kf.x); K_lds[row][col + 1] = f2bf(kf.y);
                K_lds[row][col + 2] = f2bf(kf.z); K_lds[row][col + 3] = f2bf(kf.w);
                float4 vf = vs[idx];
                Vt_lds[col + 0][row] = f2bf(vf.x); Vt_lds[col + 1][row] = f2bf(vf.y);
                Vt_lds[col + 2][row] = f2bf(vf.z); Vt_lds[col + 3][row] = f2bf(vf.w);
            }
        }
        __syncthreads();
        floatx4 s_acc[4];
        #pragma unroll
        for (int n = 0; n < 4; ++n) {
            const short8 k0 = *(const short8*)&K_lds[n * 16 + l15][dofs];
            const short8 k1 = *(const short8*)&K_lds[n * 16 + l15][dofs + 32];
            floatx4 acc = {0.0f, 0.0f, 0.0f, 0.0f};
            acc = __builtin_amdgcn_mfma_f32_16x16x32_bf16(qfrag[0], k0, acc, 0, 0, 0);
            acc = __builtin_amdgcn_mfma_f32_16x16x32_bf16(qfrag[1], k1, acc, 0, 0, 0);
            s_acc[n] = acc;
        }
        if (t == qi) {
            #pragma unroll
            for (int n = 0; n < 4; ++n)
                #pragma unroll
                for (int r = 0; r < 4; ++r) {
                    int qr = wv * 16 + lg * 4 + r;
                    int kc = n * 16 + l15;
                    if (kc > qr) s_acc[n][r] = -1e30f;
                }
        }
        #pragma unroll
        for (int r = 0; r < 4; ++r) {
            float rmax = fmaxf(fmaxf(s_acc[0][r], s_acc[1][r]),
                               fmaxf(s_acc[2][r], s_acc[3][r]));
            rmax = fmaxf(rmax, __shfl_xor(rmax, 1));
            rmax = fmaxf(rmax, __shfl_xor(rmax, 2));
            rmax = fmaxf(rmax, __shfl_xor(rmax, 4));
            rmax = fmaxf(rmax, __shfl_xor(rmax, 8));
            float mnew  = fmaxf(m_r[r], rmax);
            float alpha = __expf(m_r[r] - mnew);
            m_r[r] = mnew;
            l_r[r] *= alpha;
            #pragma unroll
            for (int dt = 0; dt < 4; ++dt) o_acc[dt][r] *= alpha;
            #pragma unroll
            for (int n = 0; n < 4; ++n) {
                float p = __expf(s_acc[n][r] - mnew);
                l_r[r] += p;
                P_lds[wv][lg * 4 + r][n * 16 + l15] = f2bf(p);
            }
        }
        asm volatile("s_waitcnt lgkmcnt(0)" ::: "memory");
        const short8 p0 = *(const short8*)&P_lds[wv][l15][dofs];
        const short8 p1 = *(const short8*)&P_lds[wv][l15][dofs + 32];
        #pragma unroll
        for (int dt = 0; dt < 4; ++dt) {
            const short8 v0 = *(const short8*)&Vt_lds[dt * 16 + l15][dofs];
            const short8 v1 = *(const short8*)&Vt_lds[dt * 16 + l15][dofs + 32];
            o_acc[dt] = __builtin_amdgcn_mfma_f32_16x16x32_bf16(p0, v0, o_acc[dt], 0, 0, 0);
            o_acc[dt] = __builtin_amdgcn_mfma_f32_16x16x32_bf16(p1, v1, o_acc[dt], 0, 0, 0);
        }
    }
    #pragma unroll
    for (int r = 0; r < 4; ++r) {
        float l = l_r[r];
        l += __shfl_xor(l, 1);
        l += __shfl_xor(l, 2);
        l += __shfl_xor(l, 4);
        l += __shfl_xor(l, 8);
        l_r[r] = 1.0f / l;
    }
    #pragma unroll
    for (int dt = 0; dt < 4; ++dt)
        #pragma unroll
        for (int r = 0; r < 4; ++r) {
            int row = qbase + wv * 16 + lg * 4 + r;
            Op[(size_t)row * HD + dt * 16 + l15] = o_acc[dt][r] * l_r[r];
        }
}

extern "C" void kernel_launch(void* const* d_in, const int* in_sizes, int n_in,
                              void* d_out, int out_size, void* d_ws, size_t ws_size,
                              hipStream_t stream) {
    const float* q = (const float*)d_in[0];
    const float* k = (const float*)d_in[1];
    const float* v = (const float*)d_in[2];
    float* o = (float*)d_out;
    (void)in_sizes; (void)n_in; (void)out_size;

    const size_t elems = (size_t)NBH * SEQ * HD;
    const size_t need  = 2 * elems * sizeof(short);
    if (ws_size >= need) {
        short* kb = (short*)d_ws;
        short* vt = kb + elems;
        conv_k_kernel<<<dim3(elems / (256 * 8)), dim3(256), 0, stream>>>(k, kb);
        trans_v_kernel<<<dim3(NBH * 32), dim3(256), 0, stream>>>(v, vt);
        fa_fwd_v4<<<dim3(NBH * NQT), dim3(256), 0, stream>>>(q, kb, vt, o);
    } else {
        fa_fwd_v1<<<dim3(NBH * NQT), dim3(256), 0, stream>>>(q, k, v, o);
    }
}